// Round 1
// baseline (2972.117 us; speedup 1.0000x reference)
//
#include <hip/hip_runtime.h>
#include <hip/hip_bf16.h>
#include <math.h>

// Problem constants
#define B_    32
#define N_    1024
#define DIM_  512
#define HEAD_ 8
#define HD_   64        // head dim
#define WSP   32        // sqrt(N)
#define M2    256       // kv spatial positions (16*16)
#define CDIM  1024      // 2*DIM
#define KCONV 4608      // DIM*3*3
#define EPS_  1e-5f
#define SCALE_ 0.044194173824159216f  // DIM^-0.5

// ---------------------------------------------------------------------------
// Generic fp32 tiled GEMM: C[M x N] = A[M x K] * B[N x K]^T
// 64x64 tile, BK=16, 256 threads, 4x4 accumulators per thread.
// M % 64 == 0, N % 64 == 0, K % 16 == 0 (true for all uses here).
// ---------------------------------------------------------------------------
__global__ __launch_bounds__(256) void gemm_abT_kernel(
    const float* __restrict__ A, const float* __restrict__ Bm,
    float* __restrict__ C, int M, int N, int K) {
  __shared__ float As[16][65];
  __shared__ float Bs[16][65];
  const int tid = threadIdx.x;
  const int bm = blockIdx.y * 64, bn = blockIdx.x * 64;
  const int tx = tid & 15, ty = tid >> 4;
  float acc[4][4] = {};
  for (int k0 = 0; k0 < K; k0 += 16) {
#pragma unroll
    for (int it = 0; it < 4; ++it) {
      int idx = it * 256 + tid;
      int m = idx >> 4, k = idx & 15;
      As[k][m] = A[(size_t)(bm + m) * K + k0 + k];
      Bs[k][m] = Bm[(size_t)(bn + m) * K + k0 + k];
    }
    __syncthreads();
#pragma unroll
    for (int k = 0; k < 16; ++k) {
      float a0[4], b0[4];
#pragma unroll
      for (int i = 0; i < 4; ++i) a0[i] = As[k][ty * 4 + i];
#pragma unroll
      for (int j = 0; j < 4; ++j) b0[j] = Bs[k][tx * 4 + j];
#pragma unroll
      for (int i = 0; i < 4; ++i)
#pragma unroll
        for (int j = 0; j < 4; ++j)
          acc[i][j] += a0[i] * b0[j];
    }
    __syncthreads();
  }
#pragma unroll
  for (int i = 0; i < 4; ++i) {
    float4 o = make_float4(acc[i][0], acc[i][1], acc[i][2], acc[i][3]);
    *reinterpret_cast<float4*>(&C[(size_t)(bm + ty * 4 + i) * N + bn + tx * 4]) = o;
  }
}

// ---------------------------------------------------------------------------
// Conv 3x3 stride-2 pad-1 (512 -> 1024 ch) as im2col GEMM + bias.
// Output kv[p=(b*256 + w2*16 + h2)][oc], p in [0,8192), oc in [0,1024).
// A[p][kk] gathered on the fly; B = conv_w flat [1024 x 4608] row-major.
// ---------------------------------------------------------------------------
__global__ __launch_bounds__(256) void conv_gemm_kernel(
    const float* __restrict__ feats, const float* __restrict__ Wc,
    const float* __restrict__ bias, float* __restrict__ kv) {
  __shared__ float As[16][65];
  __shared__ float Bs[16][65];
  const int tid = threadIdx.x;
  const int bm = blockIdx.y * 64, bn = blockIdx.x * 64;
  const int tx = tid & 15, ty = tid >> 4;
  float acc[4][4] = {};
  for (int k0 = 0; k0 < KCONV; k0 += 16) {
#pragma unroll
    for (int it = 0; it < 4; ++it) {
      int idx = it * 256 + tid;
      int m = idx >> 4, kl = idx & 15;
      int p = bm + m;
      int b = p >> 8, sp = p & 255;
      int w2 = sp >> 4, h2 = sp & 15;
      int kk = k0 + kl;
      int ic = kk / 9, r = kk - ic * 9;
      int kh = r / 3, kw = r - kh * 3;
      int iw = 2 * w2 - 1 + kh, ih = 2 * h2 - 1 + kw;
      float v = 0.f;
      if ((unsigned)iw < 32u && (unsigned)ih < 32u)
        v = feats[((size_t)b * N_ + iw * WSP + ih) * DIM_ + ic];
      As[kl][m] = v;
      Bs[kl][m] = Wc[(size_t)(bn + m) * KCONV + kk];
    }
    __syncthreads();
#pragma unroll
    for (int k = 0; k < 16; ++k) {
      float a0[4], b0[4];
#pragma unroll
      for (int i = 0; i < 4; ++i) a0[i] = As[k][ty * 4 + i];
#pragma unroll
      for (int j = 0; j < 4; ++j) b0[j] = Bs[k][tx * 4 + j];
#pragma unroll
      for (int i = 0; i < 4; ++i)
#pragma unroll
        for (int j = 0; j < 4; ++j)
          acc[i][j] += a0[i] * b0[j];
    }
    __syncthreads();
  }
#pragma unroll
  for (int i = 0; i < 4; ++i) {
    int row = bm + ty * 4 + i;
    int col = bn + tx * 4;
    float4 o = make_float4(acc[0 + i][0] + bias[col + 0],
                           acc[0 + i][1] + bias[col + 1],
                           acc[0 + i][2] + bias[col + 2],
                           acc[0 + i][3] + bias[col + 3]);
    *reinterpret_cast<float4*>(&kv[(size_t)row * CDIM + col]) = o;
  }
}

// ---------------------------------------------------------------------------
// LayerNorm over last dim (1024) of kv[8192][1024], in place. gamma/beta 1024.
// One block (256 threads) per row; exactly one float4 per thread.
// ---------------------------------------------------------------------------
__global__ __launch_bounds__(256) void ln_kernel(
    float* __restrict__ kv, const float* __restrict__ gamma,
    const float* __restrict__ beta) {
  const int p = blockIdx.x, tid = threadIdx.x;
  float4* row = reinterpret_cast<float4*>(kv + (size_t)p * CDIM);
  float4 x = row[tid];
  float s = x.x + x.y + x.z + x.w;
  float ss = x.x * x.x + x.y * x.y + x.z * x.z + x.w * x.w;
#pragma unroll
  for (int off = 32; off > 0; off >>= 1) {
    s += __shfl_down(s, off);
    ss += __shfl_down(ss, off);
  }
  __shared__ float sb[4], ssb[4];
  if ((tid & 63) == 0) { sb[tid >> 6] = s; ssb[tid >> 6] = ss; }
  __syncthreads();
  float tot = sb[0] + sb[1] + sb[2] + sb[3];
  float tot2 = ssb[0] + ssb[1] + ssb[2] + ssb[3];
  float mu = tot * (1.f / CDIM);
  float var = tot2 * (1.f / CDIM) - mu * mu;
  float rstd = rsqrtf(var + EPS_);
  float4 g = reinterpret_cast<const float4*>(gamma)[tid];
  float4 bb = reinterpret_cast<const float4*>(beta)[tid];
  x.x = (x.x - mu) * rstd * g.x + bb.x;
  x.y = (x.y - mu) * rstd * g.y + bb.y;
  x.z = (x.z - mu) * rstd * g.z + bb.z;
  x.w = (x.w - mu) * rstd * g.w + bb.w;
  row[tid] = x;
}

// ---------------------------------------------------------------------------
// Fused attention: one block per (b, head). K/V head-tiles (256x64 each)
// staged in LDS (128 KiB). Each thread owns 4 query rows; q + accumulator in
// registers. Softmax without max-subtraction (|s| <~ 2, exp cannot overflow).
// ---------------------------------------------------------------------------
__global__ __launch_bounds__(256) void attn_kernel(
    const float* __restrict__ q, const float* __restrict__ kv,
    float* __restrict__ attout) {
  __shared__ float Ks[M2][HD_];
  __shared__ float Vs[M2][HD_];
  const int tid = threadIdx.x;
  const int bh = blockIdx.x;  // b*8 + h
  const int b = bh >> 3, h = bh & 7;
  const float* kvbase = kv + (size_t)b * M2 * CDIM + h * HD_;
#pragma unroll
  for (int it = 0; it < 16; ++it) {
    int idx = it * 256 + tid;          // 4096 float4 slots per matrix
    int j = idx >> 4, dd = idx & 15;   // row j, float4 slot dd
    const float4* srck = reinterpret_cast<const float4*>(kvbase + (size_t)j * CDIM);
    const float4* srcv = reinterpret_cast<const float4*>(kvbase + (size_t)j * CDIM + DIM_);
    reinterpret_cast<float4*>(Ks[j])[dd] = srck[dd];
    reinterpret_cast<float4*>(Vs[j])[dd] = srcv[dd];
  }
  __syncthreads();
  for (int iq = tid; iq < N_; iq += 256) {
    const float* qrow = q + ((size_t)b * N_ + iq) * DIM_ + h * HD_;
    float qr[HD_];
#pragma unroll
    for (int dd = 0; dd < 16; ++dd) {
      float4 t = reinterpret_cast<const float4*>(qrow)[dd];
      qr[dd * 4 + 0] = t.x; qr[dd * 4 + 1] = t.y;
      qr[dd * 4 + 2] = t.z; qr[dd * 4 + 3] = t.w;
    }
    float acc[HD_] = {};
    float l = 0.f;
    for (int j = 0; j < M2; ++j) {
      float sdot = 0.f;
#pragma unroll
      for (int d = 0; d < HD_; ++d) sdot += qr[d] * Ks[j][d];
      float p = __expf(sdot * SCALE_);
      l += p;
#pragma unroll
      for (int d = 0; d < HD_; ++d) acc[d] += p * Vs[j][d];
    }
    float inv = 1.f / l;
    float* orow = attout + ((size_t)b * N_ + iq) * DIM_ + h * HD_;
#pragma unroll
    for (int dd = 0; dd < 16; ++dd) {
      float4 t = make_float4(acc[dd * 4 + 0] * inv, acc[dd * 4 + 1] * inv,
                             acc[dd * 4 + 2] * inv, acc[dd * 4 + 3] * inv);
      reinterpret_cast<float4*>(orow)[dd] = t;
    }
  }
}

// ---------------------------------------------------------------------------
extern "C" void kernel_launch(void* const* d_in, const int* in_sizes, int n_in,
                              void* d_out, int out_size, void* d_ws, size_t ws_size,
                              hipStream_t stream) {
  const float* feats  = (const float*)d_in[0];
  const float* W_q    = (const float*)d_in[1];
  const float* conv_w = (const float*)d_in[2];
  const float* conv_b = (const float*)d_in[3];
  const float* ln_g   = (const float*)d_in[4];
  const float* ln_b   = (const float*)d_in[5];
  const float* W_out  = (const float*)d_in[6];
  float* out = (float*)d_out;

  float* ws = (float*)d_ws;
  float* q      = ws;                                   // 32*1024*512  = 16.78M floats
  float* kv     = q + (size_t)B_ * N_ * DIM_;           // 32*256*1024  =  8.39M floats
  float* attout = kv + (size_t)B_ * M2 * CDIM;          // 32*1024*512  = 16.78M floats

  // q = feats @ W_q^T   (M=32768, N=512, K=512)
  gemm_abT_kernel<<<dim3(DIM_ / 64, (B_ * N_) / 64), 256, 0, stream>>>(
      feats, W_q, q, B_ * N_, DIM_, DIM_);

  // kv_pre = conv(feats) + bias   (M=8192, N=1024, K=4608)
  conv_gemm_kernel<<<dim3(CDIM / 64, (B_ * M2) / 64), 256, 0, stream>>>(
      feats, conv_w, conv_b, kv);

  // LayerNorm over channel dim
  ln_kernel<<<B_ * M2, 256, 0, stream>>>(kv, ln_g, ln_b);

  // attention -> attout
  attn_kernel<<<B_ * HEAD_, 256, 0, stream>>>(q, kv, attout);

  // out = attout @ W_out^T   (M=32768, N=512, K=512)
  gemm_abT_kernel<<<dim3(DIM_ / 64, (B_ * N_) / 64), 256, 0, stream>>>(
      attout, W_out, out, B_ * N_, DIM_, DIM_);
}

// Round 2
// 645.952 us; speedup vs baseline: 4.6011x; 4.6011x over previous
//
#include <hip/hip_runtime.h>
#include <hip/hip_bf16.h>
#include <math.h>

// Problem constants
#define B_    32
#define N_    1024
#define DIM_  512
#define HEAD_ 8
#define HD_   64        // head dim
#define WSP   32        // sqrt(N)
#define M2    256       // kv spatial positions (16*16)
#define CDIM  1024      // 2*DIM
#define KCONV 4608      // DIM*3*3
#define EPS_  1e-5f
#define SCALE_ 0.044194173824159216f  // DIM^-0.5

typedef __attribute__((ext_vector_type(8))) short bf16x8;
typedef __attribute__((ext_vector_type(4))) float f32x4_t;

__device__ __forceinline__ ushort f2b(float x) {
  __hip_bfloat16 h = __float2bfloat16(x);
  return *reinterpret_cast<const ushort*>(&h);
}
__device__ __forceinline__ float b2f(ushort u) {
  return __uint_as_float(((unsigned int)u) << 16);
}

// ---------------------------------------------------------------------------
// fp32 -> bf16 cast, 4 elems/thread
// ---------------------------------------------------------------------------
__global__ __launch_bounds__(256) void cast_f32_bf16_kernel(
    const float* __restrict__ in, ushort* __restrict__ out, int n4) {
  int i = blockIdx.x * 256 + threadIdx.x;
  if (i >= n4) return;
  float4 v = reinterpret_cast<const float4*>(in)[i];
  ushort4 o;
  o.x = f2b(v.x); o.y = f2b(v.y); o.z = f2b(v.z); o.w = f2b(v.w);
  reinterpret_cast<ushort4*>(out)[i] = o;
}

// ---------------------------------------------------------------------------
// conv_w [oc][ic*9 + tap] fp32 -> bf16 [oc][tap*512 + ic]  (K reorder so
// 8 consecutive K elems are contiguous `ic` in feats for the im2col gather)
// ---------------------------------------------------------------------------
__global__ __launch_bounds__(256) void permute_convw_kernel(
    const float* __restrict__ in, ushort* __restrict__ out) {
  int oc = blockIdx.y;
  int idx = blockIdx.x * 256 + threadIdx.x;  // [0, 4608)
  int tap = idx >> 9, ic = idx & 511;
  out[(size_t)oc * KCONV + idx] = f2b(in[(size_t)oc * KCONV + ic * 9 + tap]);
}

// ---------------------------------------------------------------------------
// MFMA bf16 GEMM: C[M x N] = A[M x K] * B[N x K]^T  (+bias, dtype per MODE)
// 128x128 tile, BK=32, 256 threads = 4 waves (2x2 of 64x64), m97-class
// 2-barrier structure with one-step register prefetch of the staging loads.
// MODE 0: A = bf16 buffer, C = f32
// MODE 1: A = bf16 buffer, C = bf16
// MODE 2: A = implicit im2col of feats_bf16 (3x3 s2 p1), C = f32 + bias
// ---------------------------------------------------------------------------
template<int MODE>
__global__ __launch_bounds__(256) void mfma_gemm_kernel(
    const ushort* __restrict__ A, const ushort* __restrict__ featsb,
    const ushort* __restrict__ Bw, float* __restrict__ Cf,
    ushort* __restrict__ Cb, const float* __restrict__ bias,
    int M, int N, int K) {
  __shared__ ushort As[128][32];
  __shared__ ushort Bs[128][32];
  const int tid = threadIdx.x;
  const int lane = tid & 63, wid = tid >> 6;
  const int wr = wid >> 1, wc = wid & 1;
  const int bm = blockIdx.y * 128, bn = blockIdx.x * 128;
  const int lrow = lane & 15, lk = lane >> 4;

  f32x4_t acc[4][4] = {};

  auto loadA = [&](int it, int k0) -> bf16x8 {
    int idx = it * 256 + tid;
    int row = idx >> 2, c8 = idx & 3;
    if (MODE == 2) {
      int p = bm + row;
      int b = p >> 8, sp = p & 255;
      int w2 = sp >> 4, h2 = sp & 15;
      int kk = k0 + c8 * 8;
      int tap = kk >> 9, ic = kk & 511;
      int kh = tap / 3, kw = tap - kh * 3;
      int iw = 2 * w2 - 1 + kh, ih = 2 * h2 - 1 + kw;
      bf16x8 v = {};
      if ((unsigned)iw < 32u && (unsigned)ih < 32u)
        v = *reinterpret_cast<const bf16x8*>(
            &featsb[((size_t)(b << 10) + iw * WSP + ih) * DIM_ + ic]);
      return v;
    } else {
      return *reinterpret_cast<const bf16x8*>(
          &A[(size_t)(bm + row) * K + k0 + c8 * 8]);
    }
  };
  auto loadB = [&](int it, int k0) -> bf16x8 {
    int idx = it * 256 + tid;
    int row = idx >> 2, c8 = idx & 3;
    return *reinterpret_cast<const bf16x8*>(
        &Bw[(size_t)(bn + row) * K + k0 + c8 * 8]);
  };

  bf16x8 ra0 = loadA(0, 0), ra1 = loadA(1, 0);
  bf16x8 rb0 = loadB(0, 0), rb1 = loadB(1, 0);
  const int NT = K >> 5;
  for (int kt = 0; kt < NT; ++kt) {
    __syncthreads();
    {
      int idx0 = tid, idx1 = 256 + tid;
      *reinterpret_cast<bf16x8*>(&As[idx0 >> 2][(idx0 & 3) * 8]) = ra0;
      *reinterpret_cast<bf16x8*>(&Bs[idx0 >> 2][(idx0 & 3) * 8]) = rb0;
      *reinterpret_cast<bf16x8*>(&As[idx1 >> 2][(idx1 & 3) * 8]) = ra1;
      *reinterpret_cast<bf16x8*>(&Bs[idx1 >> 2][(idx1 & 3) * 8]) = rb1;
    }
    __syncthreads();
    if (kt + 1 < NT) {
      int k0 = (kt + 1) << 5;
      ra0 = loadA(0, k0); ra1 = loadA(1, k0);
      rb0 = loadB(0, k0); rb1 = loadB(1, k0);
    }
    bf16x8 aF[4], bF[4];
#pragma unroll
    for (int m = 0; m < 4; ++m)
      aF[m] = *reinterpret_cast<const bf16x8*>(&As[wr * 64 + m * 16 + lrow][lk * 8]);
#pragma unroll
    for (int n = 0; n < 4; ++n)
      bF[n] = *reinterpret_cast<const bf16x8*>(&Bs[wc * 64 + n * 16 + lrow][lk * 8]);
#pragma unroll
    for (int m = 0; m < 4; ++m)
#pragma unroll
      for (int n = 0; n < 4; ++n)
        acc[m][n] = __builtin_amdgcn_mfma_f32_16x16x32_bf16(
            aF[m], bF[n], acc[m][n], 0, 0, 0);
  }

  // Epilogue: C/D layout col = lane&15, row = (lane>>4)*4 + reg
#pragma unroll
  for (int m = 0; m < 4; ++m) {
#pragma unroll
    for (int n = 0; n < 4; ++n) {
      int col = bn + wc * 64 + n * 16 + lrow;
#pragma unroll
      for (int r = 0; r < 4; ++r) {
        int row = bm + wr * 64 + m * 16 + lk * 4 + r;
        float v = acc[m][n][r];
        if (MODE == 2) v += bias[col];
        if (MODE == 1) Cb[(size_t)row * N + col] = f2b(v);
        else Cf[(size_t)row * N + col] = v;
      }
    }
  }
}

// ---------------------------------------------------------------------------
// LayerNorm over last dim (1024) of kv[8192][1024], in place.
// ---------------------------------------------------------------------------
__global__ __launch_bounds__(256) void ln_kernel(
    float* __restrict__ kv, const float* __restrict__ gamma,
    const float* __restrict__ beta) {
  const int p = blockIdx.x, tid = threadIdx.x;
  float4* row = reinterpret_cast<float4*>(kv + (size_t)p * CDIM);
  float4 x = row[tid];
  float s = x.x + x.y + x.z + x.w;
  float ss = x.x * x.x + x.y * x.y + x.z * x.z + x.w * x.w;
#pragma unroll
  for (int off = 32; off > 0; off >>= 1) {
    s += __shfl_down(s, off);
    ss += __shfl_down(ss, off);
  }
  __shared__ float sb[4], ssb[4];
  if ((tid & 63) == 0) { sb[tid >> 6] = s; ssb[tid >> 6] = ss; }
  __syncthreads();
  float tot = sb[0] + sb[1] + sb[2] + sb[3];
  float tot2 = ssb[0] + ssb[1] + ssb[2] + ssb[3];
  float mu = tot * (1.f / CDIM);
  float var = tot2 * (1.f / CDIM) - mu * mu;
  float rstd = rsqrtf(var + EPS_);
  float4 g = reinterpret_cast<const float4*>(gamma)[tid];
  float4 bb = reinterpret_cast<const float4*>(beta)[tid];
  x.x = (x.x - mu) * rstd * g.x + bb.x;
  x.y = (x.y - mu) * rstd * g.y + bb.y;
  x.z = (x.z - mu) * rstd * g.z + bb.z;
  x.w = (x.w - mu) * rstd * g.w + bb.w;
  row[tid] = x;
}

// ---------------------------------------------------------------------------
// Fused attention: one block per (b, head). K/V f32 head-tiles in LDS.
// q read as bf16, output written as bf16 (feeds final MFMA GEMM).
// Softmax without max-subtraction (|alpha| <~ 2.5; exp cannot overflow).
// ---------------------------------------------------------------------------
__global__ __launch_bounds__(256) void attn_kernel(
    const ushort* __restrict__ qb, const float* __restrict__ kv,
    ushort* __restrict__ attout) {
  __shared__ float Ks[M2][HD_];
  __shared__ float Vs[M2][HD_];
  const int tid = threadIdx.x;
  const int bh = blockIdx.x;  // b*8 + h
  const int b = bh >> 3, h = bh & 7;
  const float* kvbase = kv + (size_t)b * M2 * CDIM + h * HD_;
#pragma unroll
  for (int it = 0; it < 16; ++it) {
    int idx = it * 256 + tid;
    int j = idx >> 4, dd = idx & 15;
    const float4* srck = reinterpret_cast<const float4*>(kvbase + (size_t)j * CDIM);
    const float4* srcv = reinterpret_cast<const float4*>(kvbase + (size_t)j * CDIM + DIM_);
    reinterpret_cast<float4*>(Ks[j])[dd] = srck[dd];
    reinterpret_cast<float4*>(Vs[j])[dd] = srcv[dd];
  }
  __syncthreads();
  for (int iq = tid; iq < N_; iq += 256) {
    const ushort* qrow = qb + ((size_t)b * N_ + iq) * DIM_ + h * HD_;
    float qr[HD_];
#pragma unroll
    for (int dd = 0; dd < 8; ++dd) {
      bf16x8 t = *reinterpret_cast<const bf16x8*>(&qrow[dd * 8]);
#pragma unroll
      for (int j = 0; j < 8; ++j) qr[dd * 8 + j] = b2f((ushort)t[j]);
    }
    float acc[HD_] = {};
    float l = 0.f;
    for (int j = 0; j < M2; ++j) {
      float sdot = 0.f;
#pragma unroll
      for (int d = 0; d < HD_; ++d) sdot += qr[d] * Ks[j][d];
      float p = __expf(sdot * SCALE_);
      l += p;
#pragma unroll
      for (int d = 0; d < HD_; ++d) acc[d] += p * Vs[j][d];
    }
    float inv = 1.f / l;
    ushort* orow = attout + ((size_t)b * N_ + iq) * DIM_ + h * HD_;
#pragma unroll
    for (int dd = 0; dd < 16; ++dd) {
      ushort4 o;
      o.x = f2b(acc[dd * 4 + 0] * inv);
      o.y = f2b(acc[dd * 4 + 1] * inv);
      o.z = f2b(acc[dd * 4 + 2] * inv);
      o.w = f2b(acc[dd * 4 + 3] * inv);
      *reinterpret_cast<ushort4*>(&orow[dd * 4]) = o;
    }
  }
}

// ---------------------------------------------------------------------------
extern "C" void kernel_launch(void* const* d_in, const int* in_sizes, int n_in,
                              void* d_out, int out_size, void* d_ws, size_t ws_size,
                              hipStream_t stream) {
  const float* feats  = (const float*)d_in[0];
  const float* W_q    = (const float*)d_in[1];
  const float* conv_w = (const float*)d_in[2];
  const float* conv_b = (const float*)d_in[3];
  const float* ln_g   = (const float*)d_in[4];
  const float* ln_b   = (const float*)d_in[5];
  const float* W_out  = (const float*)d_in[6];
  float* out = (float*)d_out;

  char* ws = (char*)d_ws;
  ushort* featsb = (ushort*)ws;              ws += (size_t)B_ * N_ * DIM_ * 2;   // 33.5 MB
  ushort* qb     = (ushort*)ws;              ws += (size_t)B_ * N_ * DIM_ * 2;   // 33.5 MB
  ushort* attob  = (ushort*)ws;              ws += (size_t)B_ * N_ * DIM_ * 2;   // 33.5 MB
  float*  kv     = (float*)ws;               ws += (size_t)B_ * M2 * CDIM * 4;   // 33.5 MB
  ushort* convwb = (ushort*)ws;              ws += (size_t)CDIM * KCONV * 2;     //  9.4 MB
  ushort* wqb    = (ushort*)ws;              ws += (size_t)DIM_ * DIM_ * 2;      //  0.5 MB
  ushort* woutb  = (ushort*)ws;              ws += (size_t)DIM_ * DIM_ * 2;      //  0.5 MB

  // casts
  cast_f32_bf16_kernel<<<16384, 256, 0, stream>>>(feats, featsb, (B_ * N_ * DIM_) / 4);
  cast_f32_bf16_kernel<<<256, 256, 0, stream>>>(W_q, wqb, (DIM_ * DIM_) / 4);
  cast_f32_bf16_kernel<<<256, 256, 0, stream>>>(W_out, woutb, (DIM_ * DIM_) / 4);
  permute_convw_kernel<<<dim3(18, CDIM), 256, 0, stream>>>(conv_w, convwb);

  // q = feats @ W_q^T  -> bf16   (M=32768, N=512, K=512)
  mfma_gemm_kernel<1><<<dim3(DIM_ / 128, (B_ * N_) / 128), 256, 0, stream>>>(
      featsb, nullptr, wqb, nullptr, qb, nullptr, B_ * N_, DIM_, DIM_);

  // kv_pre = conv(feats) + bias  (M=8192, N=1024, K=4608, implicit im2col)
  mfma_gemm_kernel<2><<<dim3(CDIM / 128, (B_ * M2) / 128), 256, 0, stream>>>(
      nullptr, featsb, convwb, kv, nullptr, conv_b, B_ * M2, CDIM, KCONV);

  // LayerNorm over channel dim
  ln_kernel<<<B_ * M2, 256, 0, stream>>>(kv, ln_g, ln_b);

  // attention -> attob (bf16)
  attn_kernel<<<B_ * HEAD_, 256, 0, stream>>>(qb, kv, attob);

  // out = attout @ W_out^T  (M=32768, N=512, K=512)
  mfma_gemm_kernel<0><<<dim3(DIM_ / 128, (B_ * N_) / 128), 256, 0, stream>>>(
      attob, nullptr, woutb, out, nullptr, nullptr, B_ * N_, DIM_, DIM_);
}

// Round 3
// 301.096 us; speedup vs baseline: 9.8710x; 2.1453x over previous
//
#include <hip/hip_runtime.h>
#include <hip/hip_bf16.h>
#include <math.h>

// Problem constants
#define B_    32
#define N_    1024
#define DIM_  512
#define HEAD_ 8
#define HD_   64        // head dim
#define WSP   32        // sqrt(N)
#define M2    256       // kv spatial positions (16*16)
#define CDIM  1024      // 2*DIM
#define KCONV 4608      // DIM*3*3
#define EPS_  1e-5f
#define SCALE_ 0.044194173824159216f  // DIM^-0.5

typedef __attribute__((ext_vector_type(8))) short bf16x8;
typedef __attribute__((ext_vector_type(4))) float f32x4_t;

__device__ __forceinline__ ushort f2b(float x) {
  __hip_bfloat16 h = __float2bfloat16(x);
  return *reinterpret_cast<const ushort*>(&h);
}

// ---------------------------------------------------------------------------
// fp32 -> bf16 cast, 4 elems/thread
// ---------------------------------------------------------------------------
__global__ __launch_bounds__(256) void cast_f32_bf16_kernel(
    const float* __restrict__ in, ushort* __restrict__ out, int n4) {
  int i = blockIdx.x * 256 + threadIdx.x;
  if (i >= n4) return;
  float4 v = reinterpret_cast<const float4*>(in)[i];
  ushort4 o;
  o.x = f2b(v.x); o.y = f2b(v.y); o.z = f2b(v.z); o.w = f2b(v.w);
  reinterpret_cast<ushort4*>(out)[i] = o;
}

// ---------------------------------------------------------------------------
// conv_w [oc][ic*9 + tap] fp32 -> bf16 [oc][tap*512 + ic]
// ---------------------------------------------------------------------------
__global__ __launch_bounds__(256) void permute_convw_kernel(
    const float* __restrict__ in, ushort* __restrict__ out) {
  int oc = blockIdx.y;
  int idx = blockIdx.x * 256 + threadIdx.x;  // [0, 4608)
  int tap = idx >> 9, ic = idx & 511;
  out[(size_t)oc * KCONV + idx] = f2b(in[(size_t)oc * KCONV + ic * 9 + tap]);
}

// ---------------------------------------------------------------------------
// MFMA bf16 GEMM: C[M x N] = A[M x K] * B[N x K]^T
// MODE 0: A = bf16 buffer, C = f32
// MODE 1: A = bf16 buffer, C = bf16
// MODE 2: A = implicit im2col of feats_bf16 (3x3 s2 p1), C = f32 + bias
// ---------------------------------------------------------------------------
template<int MODE>
__global__ __launch_bounds__(256) void mfma_gemm_kernel(
    const ushort* __restrict__ A, const ushort* __restrict__ featsb,
    const ushort* __restrict__ Bw, float* __restrict__ Cf,
    ushort* __restrict__ Cb, const float* __restrict__ bias,
    int M, int N, int K) {
  __shared__ ushort As[128][32];
  __shared__ ushort Bs[128][32];
  const int tid = threadIdx.x;
  const int lane = tid & 63, wid = tid >> 6;
  const int wr = wid >> 1, wc = wid & 1;
  const int bm = blockIdx.y * 128, bn = blockIdx.x * 128;
  const int lrow = lane & 15, lk = lane >> 4;

  f32x4_t acc[4][4] = {};

  auto loadA = [&](int it, int k0) -> bf16x8 {
    int idx = it * 256 + tid;
    int row = idx >> 2, c8 = idx & 3;
    if (MODE == 2) {
      int p = bm + row;
      int b = p >> 8, sp = p & 255;
      int w2 = sp >> 4, h2 = sp & 15;
      int kk = k0 + c8 * 8;
      int tap = kk >> 9, ic = kk & 511;
      int kh = tap / 3, kw = tap - kh * 3;
      int iw = 2 * w2 - 1 + kh, ih = 2 * h2 - 1 + kw;
      bf16x8 v = {};
      if ((unsigned)iw < 32u && (unsigned)ih < 32u)
        v = *reinterpret_cast<const bf16x8*>(
            &featsb[((size_t)(b << 10) + iw * WSP + ih) * DIM_ + ic]);
      return v;
    } else {
      return *reinterpret_cast<const bf16x8*>(
          &A[(size_t)(bm + row) * K + k0 + c8 * 8]);
    }
  };
  auto loadB = [&](int it, int k0) -> bf16x8 {
    int idx = it * 256 + tid;
    int row = idx >> 2, c8 = idx & 3;
    return *reinterpret_cast<const bf16x8*>(
        &Bw[(size_t)(bn + row) * K + k0 + c8 * 8]);
  };

  bf16x8 ra0 = loadA(0, 0), ra1 = loadA(1, 0);
  bf16x8 rb0 = loadB(0, 0), rb1 = loadB(1, 0);
  const int NT = K >> 5;
  for (int kt = 0; kt < NT; ++kt) {
    __syncthreads();
    {
      int idx0 = tid, idx1 = 256 + tid;
      *reinterpret_cast<bf16x8*>(&As[idx0 >> 2][(idx0 & 3) * 8]) = ra0;
      *reinterpret_cast<bf16x8*>(&Bs[idx0 >> 2][(idx0 & 3) * 8]) = rb0;
      *reinterpret_cast<bf16x8*>(&As[idx1 >> 2][(idx1 & 3) * 8]) = ra1;
      *reinterpret_cast<bf16x8*>(&Bs[idx1 >> 2][(idx1 & 3) * 8]) = rb1;
    }
    __syncthreads();
    if (kt + 1 < NT) {
      int k0 = (kt + 1) << 5;
      ra0 = loadA(0, k0); ra1 = loadA(1, k0);
      rb0 = loadB(0, k0); rb1 = loadB(1, k0);
    }
    bf16x8 aF[4], bF[4];
#pragma unroll
    for (int m = 0; m < 4; ++m)
      aF[m] = *reinterpret_cast<const bf16x8*>(&As[wr * 64 + m * 16 + lrow][lk * 8]);
#pragma unroll
    for (int n = 0; n < 4; ++n)
      bF[n] = *reinterpret_cast<const bf16x8*>(&Bs[wc * 64 + n * 16 + lrow][lk * 8]);
#pragma unroll
    for (int m = 0; m < 4; ++m)
#pragma unroll
      for (int n = 0; n < 4; ++n)
        acc[m][n] = __builtin_amdgcn_mfma_f32_16x16x32_bf16(
            aF[m], bF[n], acc[m][n], 0, 0, 0);
  }

#pragma unroll
  for (int m = 0; m < 4; ++m) {
#pragma unroll
    for (int n = 0; n < 4; ++n) {
      int col = bn + wc * 64 + n * 16 + lrow;
#pragma unroll
      for (int r = 0; r < 4; ++r) {
        int row = bm + wr * 64 + m * 16 + lk * 4 + r;
        float v = acc[m][n][r];
        if (MODE == 2) v += bias[col];
        if (MODE == 1) Cb[(size_t)row * N + col] = f2b(v);
        else Cf[(size_t)row * N + col] = v;
      }
    }
  }
}

// ---------------------------------------------------------------------------
// LayerNorm over last dim (1024) of conv output kv[8192][1024] (f32), writing
// per-head bf16 tiles: Kb[bh][256][64], Vb[bh][256][64].
// One block per row p = b*256 + j; thread owns 4 channels.
// ---------------------------------------------------------------------------
__global__ __launch_bounds__(256) void ln_kernel(
    const float* __restrict__ kvin, const float* __restrict__ gamma,
    const float* __restrict__ beta, ushort* __restrict__ Kb,
    ushort* __restrict__ Vb) {
  const int p = blockIdx.x, tid = threadIdx.x;
  float4 x = reinterpret_cast<const float4*>(kvin + (size_t)p * CDIM)[tid];
  float s = x.x + x.y + x.z + x.w;
  float ss = x.x * x.x + x.y * x.y + x.z * x.z + x.w * x.w;
#pragma unroll
  for (int off = 32; off > 0; off >>= 1) {
    s += __shfl_down(s, off);
    ss += __shfl_down(ss, off);
  }
  __shared__ float sb[4], ssb[4];
  if ((tid & 63) == 0) { sb[tid >> 6] = s; ssb[tid >> 6] = ss; }
  __syncthreads();
  float tot = sb[0] + sb[1] + sb[2] + sb[3];
  float tot2 = ssb[0] + ssb[1] + ssb[2] + ssb[3];
  float mu = tot * (1.f / CDIM);
  float var = tot2 * (1.f / CDIM) - mu * mu;
  float rstd = rsqrtf(var + EPS_);
  float4 g = reinterpret_cast<const float4*>(gamma)[tid];
  float4 bb = reinterpret_cast<const float4*>(beta)[tid];
  ushort4 o;
  o.x = f2b((x.x - mu) * rstd * g.x + bb.x);
  o.y = f2b((x.y - mu) * rstd * g.y + bb.y);
  o.z = f2b((x.z - mu) * rstd * g.z + bb.z);
  o.w = f2b((x.w - mu) * rstd * g.w + bb.w);
  int b = p >> 8, j = p & 255;
  int c = tid * 4;
  if (c < DIM_) {
    int h = c >> 6, d = c & 63;
    *reinterpret_cast<ushort4*>(&Kb[(((size_t)(b * 8 + h)) * M2 + j) * HD_ + d]) = o;
  } else {
    int c2 = c - DIM_;
    int h = c2 >> 6, d = c2 & 63;
    *reinterpret_cast<ushort4*>(&Vb[(((size_t)(b * 8 + h)) * M2 + j) * HD_ + d]) = o;
  }
}

// ---------------------------------------------------------------------------
// MFMA attention. One block per (qt, bh): 4 waves, each 32 q-rows.
// LDS (128 KiB exactly): K swizzled [256][64], V^T swizzled [64][256],
// P per-wave swizzled [32][256]. All bf16.
// ---------------------------------------------------------------------------
__global__ __launch_bounds__(256) void attn_mfma_kernel(
    const ushort* __restrict__ qb, const ushort* __restrict__ Kb,
    const ushort* __restrict__ Vb, ushort* __restrict__ attob) {
  __shared__ __align__(16) char lds[131072];
  char* lp = lds;
  const int tid = threadIdx.x;
  const int lane = tid & 63, wid = tid >> 6;
  const int lr = lane & 15, lk = lane >> 4;
  const int bh = blockIdx.y;
  const int b = bh >> 3, h = bh & 7;
  const int qt = blockIdx.x;

  // byte-address helpers (XOR swizzle, involution on write & read sides)
  auto ks_byte = [](int j, int d) -> int {            // K[256][64]
    return (j << 7) + (((d << 1)) ^ ((j & 7) << 4));
  };
  auto vt_byte = [](int d, int j) -> int {            // V^T[64][256]
    return 32768 + (d << 9) + (((j << 1)) ^ ((d & 7) << 4));
  };
  auto p_byte = [](int w, int q5, int kv) -> int {    // P per wave [32][256]
    return 65536 + (w << 14) + (q5 << 9) + (((kv << 1)) ^ ((q5 & 7) << 4));
  };

  // ---- stage K (swizzled) and V^T (transposed, swizzled) ----
  const ushort* Khead = Kb + (size_t)bh * M2 * HD_;
  const ushort* Vhead = Vb + (size_t)bh * M2 * HD_;
#pragma unroll
  for (int it = 0; it < 8; ++it) {
    int idx = it * 256 + tid;
    int j = idx >> 3, d0 = (idx & 7) * 8;
    bf16x8 kvec = *reinterpret_cast<const bf16x8*>(Khead + j * HD_ + d0);
    *reinterpret_cast<bf16x8*>(lp + ks_byte(j, d0)) = kvec;
    bf16x8 vvec = *reinterpret_cast<const bf16x8*>(Vhead + j * HD_ + d0);
#pragma unroll
    for (int s = 0; s < 8; ++s)
      *reinterpret_cast<ushort*>(lp + vt_byte(d0 + s, j)) = (ushort)vvec[s];
  }
  __syncthreads();

  // ---- Q fragments (registers, from global) ----
  const int qbase = qt * 128 + wid * 32;
  bf16x8 qf[2][2];
#pragma unroll
  for (int mf = 0; mf < 2; ++mf)
#pragma unroll
    for (int ks = 0; ks < 2; ++ks)
      qf[mf][ks] = *reinterpret_cast<const bf16x8*>(
          qb + ((size_t)(b * N_ + qbase + mf * 16 + lr)) * DIM_ + h * HD_ + ks * 32 + lk * 8);

  // ---- QK^T: S[32 q][256 kv] ----
  f32x4_t sacc[2][16] = {};
#pragma unroll
  for (int ks = 0; ks < 2; ++ks) {
#pragma unroll
    for (int nj = 0; nj < 16; ++nj) {
      bf16x8 kf = *reinterpret_cast<const bf16x8*>(
          lp + ks_byte(nj * 16 + lr, ks * 32 + lk * 8));
      sacc[0][nj] = __builtin_amdgcn_mfma_f32_16x16x32_bf16(qf[0][ks], kf, sacc[0][nj], 0, 0, 0);
      sacc[1][nj] = __builtin_amdgcn_mfma_f32_16x16x32_bf16(qf[1][ks], kf, sacc[1][nj], 0, 0, 0);
    }
  }

  // ---- softmax (no max-subtraction; alpha ~ N(0, 0.016)) + P -> LDS ----
  float linv[2][4];
#pragma unroll
  for (int mf = 0; mf < 2; ++mf) {
#pragma unroll
    for (int r = 0; r < 4; ++r) {
      float pv[16];
      float sum = 0.f;
#pragma unroll
      for (int nj = 0; nj < 16; ++nj) {
        pv[nj] = __expf(sacc[mf][nj][r] * SCALE_);
        sum += pv[nj];
      }
      sum += __shfl_xor(sum, 1);
      sum += __shfl_xor(sum, 2);
      sum += __shfl_xor(sum, 4);
      sum += __shfl_xor(sum, 8);
      linv[mf][r] = 1.f / sum;
      int q5 = mf * 16 + lk * 4 + r;
#pragma unroll
      for (int nj = 0; nj < 16; ++nj)
        *reinterpret_cast<ushort*>(lp + p_byte(wid, q5, nj * 16 + lr)) = f2b(pv[nj]);
    }
  }

  // ---- PV: O[32 q][64 d] ----
  f32x4_t oacc[2][4] = {};
#pragma unroll
  for (int ks2 = 0; ks2 < 8; ++ks2) {
    bf16x8 pf0 = *reinterpret_cast<const bf16x8*>(lp + p_byte(wid, lr, ks2 * 32 + lk * 8));
    bf16x8 pf1 = *reinterpret_cast<const bf16x8*>(lp + p_byte(wid, 16 + lr, ks2 * 32 + lk * 8));
#pragma unroll
    for (int df = 0; df < 4; ++df) {
      bf16x8 vf = *reinterpret_cast<const bf16x8*>(
          lp + vt_byte(df * 16 + lr, ks2 * 32 + lk * 8));
      oacc[0][df] = __builtin_amdgcn_mfma_f32_16x16x32_bf16(pf0, vf, oacc[0][df], 0, 0, 0);
      oacc[1][df] = __builtin_amdgcn_mfma_f32_16x16x32_bf16(pf1, vf, oacc[1][df], 0, 0, 0);
    }
  }

  // ---- epilogue: scale by 1/l, write bf16 ----
#pragma unroll
  for (int mf = 0; mf < 2; ++mf)
#pragma unroll
    for (int df = 0; df < 4; ++df)
#pragma unroll
      for (int r = 0; r < 4; ++r) {
        int qrow = qbase + mf * 16 + lk * 4 + r;
        int dcol = df * 16 + lr;
        float val = oacc[mf][df][r] * linv[mf][r];
        attob[((size_t)(b * N_ + qrow)) * DIM_ + h * HD_ + dcol] = f2b(val);
      }
}

// ---------------------------------------------------------------------------
extern "C" void kernel_launch(void* const* d_in, const int* in_sizes, int n_in,
                              void* d_out, int out_size, void* d_ws, size_t ws_size,
                              hipStream_t stream) {
  const float* feats  = (const float*)d_in[0];
  const float* W_q    = (const float*)d_in[1];
  const float* conv_w = (const float*)d_in[2];
  const float* conv_b = (const float*)d_in[3];
  const float* ln_g   = (const float*)d_in[4];
  const float* ln_b   = (const float*)d_in[5];
  const float* W_out  = (const float*)d_in[6];
  float* out = (float*)d_out;

  char* ws = (char*)d_ws;
  ushort* featsb = (ushort*)ws;  ws += (size_t)B_ * N_ * DIM_ * 2;    // 33.5 MB
  ushort* qb     = (ushort*)ws;  ws += (size_t)B_ * N_ * DIM_ * 2;    // 33.5 MB
  ushort* attob  = (ushort*)ws;  ws += (size_t)B_ * N_ * DIM_ * 2;    // 33.5 MB
  float*  kvf    = (float*)ws;   ws += (size_t)B_ * M2 * CDIM * 4;    // 33.5 MB
  ushort* convwb = (ushort*)ws;  ws += (size_t)CDIM * KCONV * 2;      //  9.4 MB
  ushort* wqb    = (ushort*)ws;  ws += (size_t)DIM_ * DIM_ * 2;       //  0.5 MB
  ushort* woutb  = (ushort*)ws;  ws += (size_t)DIM_ * DIM_ * 2;       //  0.5 MB
  ushort* Kb     = (ushort*)ws;  ws += (size_t)B_ * HEAD_ * M2 * HD_ * 2;  // 8.4 MB
  ushort* Vb     = (ushort*)ws;  ws += (size_t)B_ * HEAD_ * M2 * HD_ * 2;  // 8.4 MB

  // casts
  cast_f32_bf16_kernel<<<16384, 256, 0, stream>>>(feats, featsb, (B_ * N_ * DIM_) / 4);
  cast_f32_bf16_kernel<<<256, 256, 0, stream>>>(W_q, wqb, (DIM_ * DIM_) / 4);
  cast_f32_bf16_kernel<<<256, 256, 0, stream>>>(W_out, woutb, (DIM_ * DIM_) / 4);
  permute_convw_kernel<<<dim3(18, CDIM), 256, 0, stream>>>(conv_w, convwb);

  // q = feats @ W_q^T  -> bf16
  mfma_gemm_kernel<1><<<dim3(DIM_ / 128, (B_ * N_) / 128), 256, 0, stream>>>(
      featsb, nullptr, wqb, nullptr, qb, nullptr, B_ * N_, DIM_, DIM_);

  // kv_pre = conv(feats) + bias (implicit im2col)
  mfma_gemm_kernel<2><<<dim3(CDIM / 128, (B_ * M2) / 128), 256, 0, stream>>>(
      nullptr, featsb, convwb, kvf, nullptr, conv_b, B_ * M2, CDIM, KCONV);

  // LayerNorm -> per-head bf16 K/V tiles
  ln_kernel<<<B_ * M2, 256, 0, stream>>>(kvf, ln_g, ln_b, Kb, Vb);

  // MFMA attention -> attob (bf16)
  attn_mfma_kernel<<<dim3(N_ / 128, B_ * HEAD_), 256, 0, stream>>>(qb, Kb, Vb, attob);

  // out = attout @ W_out^T
  mfma_gemm_kernel<0><<<dim3(DIM_ / 128, (B_ * N_) / 128), 256, 0, stream>>>(
      attob, nullptr, woutb, out, nullptr, nullptr, B_ * N_, DIM_, DIM_);
}